// Round 2
// baseline (1081.068 us; speedup 1.0000x reference)
//
#include <hip/hip_runtime.h>

// ---------------------------------------------------------------------------
// HTGT layer: sort-by-type + bf16 MFMA pipeline
// dims (fixed by problem): N=50000 M=10000 E=100000, in=128 e=32 out=128 td=32
// R=8 etypes, T=4 ntypes, H=8 heads, hs=16
// ---------------------------------------------------------------------------

typedef __attribute__((ext_vector_type(8))) short short8;
typedef __attribute__((ext_vector_type(4))) float f32x4;

__device__ __forceinline__ unsigned short f2bf(float f){
  union { float f; unsigned u; } x; x.f = f;
  unsigned r = x.u + 0x7FFFu + ((x.u >> 16) & 1u);
  return (unsigned short)(r >> 16);
}
__device__ __forceinline__ float bf2f(unsigned short b){
  union { unsigned u; float f; } x; x.u = ((unsigned)b) << 16;
  return x.f;
}
__device__ __forceinline__ float wred(float v){
  #pragma unroll
  for(int i=1;i<64;i<<=1) v += __shfl_xor(v, i);
  return v;
}

// ---------------- setup kernels ----------------

__global__ void k_zero(int* __restrict__ p, int n){
  int i = blockIdx.x*256 + threadIdx.x;
  if(i < n) p[i] = 0;
}

__global__ void k_hist(const int* __restrict__ etype, const int* __restrict__ dst_idx,
                       const int* __restrict__ ntype,
                       int* cnt_e, int* cnt_d, int* cnt_n, int E, int M){
  int tid = blockIdx.x*256 + threadIdx.x;
  if(tid < E){ atomicAdd(&cnt_e[etype[tid]], 1); atomicAdd(&cnt_d[dst_idx[tid]], 1); }
  if(tid < M){ atomicAdd(&cnt_n[ntype[tid]], 1); }
}

__global__ __launch_bounds__(1024) void k_scan(const int* __restrict__ cnt_e, int* off_e,
                                               const int* __restrict__ cnt_n, int* off_n,
                                               const int* __restrict__ cnt_d, int* off_d, int M){
  __shared__ int part[1024];
  int tid = threadIdx.x;
  if(tid == 0){
    int s = 0;
    for(int i=0;i<8;i++){ off_e[i]=s; s+=cnt_e[i]; } off_e[8]=s;
    s = 0;
    for(int i=0;i<4;i++){ off_n[i]=s; s+=cnt_n[i]; } off_n[4]=s;
  }
  int per = (M + 1023) >> 10;
  int s = 0;
  for(int j=0;j<per;j++){ int idx = tid*per + j; if(idx < M) s += cnt_d[idx]; }
  part[tid] = s; __syncthreads();
  for(int o=1;o<1024;o<<=1){
    int v = (tid >= o) ? part[tid-o] : 0;
    __syncthreads();
    part[tid] += v;
    __syncthreads();
  }
  int run = (tid == 0) ? 0 : part[tid-1];
  for(int j=0;j<per;j++){
    int idx = tid*per + j;
    if(idx < M){ off_d[idx] = run; run += cnt_d[idx]; }
  }
  if(tid == 1023) off_d[M] = run;
}

__global__ void k_scatter(const int* __restrict__ etype, const int* __restrict__ dst_idx,
                          const int* __restrict__ ntype,
                          const int* __restrict__ off_e, int* cur_e,
                          const int* __restrict__ off_d, int* cur_d,
                          const int* __restrict__ off_n, int* cur_n,
                          int* eperm, int* dstlist, int* nperm, int* npos, int E, int M){
  int tid = blockIdx.x*256 + threadIdx.x;
  if(tid < E){
    int r = etype[tid];
    int p = off_e[r] + atomicAdd(&cur_e[r], 1);
    eperm[p] = tid;
    int d = dst_idx[tid];
    int q = off_d[d] + atomicAdd(&cur_d[d], 1);
    dstlist[q] = p;                 // store etype-sorted position
  }
  if(tid < M){
    int t = ntype[tid];
    int np = off_n[t] + atomicAdd(&cur_n[t], 1);
    npos[tid] = np;
    nperm[np] = tid;
  }
}

// convert + transpose weights to bf16 [r][n][k] layout (B-operand friendly)
__global__ void k_convw(const float* __restrict__ Wq, const float* __restrict__ Wk,
                        const float* __restrict__ Wv, const float* __restrict__ Wa,
                        unsigned short* Wq_t, unsigned short* Wk_t,
                        unsigned short* Wv_t, unsigned short* Wa_t){
  int tid = blockIdx.x*256 + threadIdx.x;
  if(tid < 131072){                                  // Wq: 8 x 128 x 128
    int r = tid >> 14, rem = tid & 16383, i = rem >> 7, o = rem & 127;
    Wq_t[(r<<14) + (o<<7) + i] = f2bf(Wq[tid]);
  } else if(tid < 294912){                           // Wk: 8 x 160 x 128
    int u = tid - 131072;
    int r = u / 20480, rem = u - r*20480, i = rem >> 7, o = rem & 127;
    Wk_t[r*20480 + o*160 + i] = f2bf(Wk[u]);
  } else if(tid < 458752){                           // Wv: 8 x 160 x 128
    int u = tid - 294912;
    int r = u / 20480, rem = u - r*20480, i = rem >> 7, o = rem & 127;
    Wv_t[r*20480 + o*160 + i] = f2bf(Wv[u]);
  } else if(tid < 524288){                           // Wa: 4 x 128 x 128
    int u = tid - 458752;
    int r = u >> 14, rem = u & 16383, i = rem >> 7, o = rem & 127;
    Wa_t[(r<<14) + (o<<7) + i] = f2bf(Wa[u]);
  }
}

// ---------------- prep: gather + temporal encode + LN, written in etype-sorted order
__global__ __launch_bounds__(256) void k_prep(
  const float* __restrict__ src_h, const float* __restrict__ src_tw, const float* __restrict__ src_tb,
  const float* __restrict__ edge_h, const float* __restrict__ date,
  const int* __restrict__ src_idx, const int* __restrict__ dst_idx, const int* __restrict__ eperm,
  const float* __restrict__ g_s, const float* __restrict__ b_s,
  const float* __restrict__ g_d, const float* __restrict__ b_d,
  unsigned short* __restrict__ dia_s, unsigned short* __restrict__ dia_d, int E)
{
  int p = blockIdx.x*4 + (threadIdx.x >> 6);
  if(p >= E) return;
  int lane = threadIdx.x & 63;
  int e = eperm[p];
  float t = date[e];
  int s = src_idx[e], d = dst_idx[e];
  { // dia_s: [sin(tw*t+tb)*h[:32], h[32:128], edge_h] -> LN(160)
    float h0 = src_h[(size_t)s*128 + lane];
    float h1 = src_h[(size_t)s*128 + 64 + lane];
    float x0 = h0, x2 = 0.f;
    if(lane < 32){
      x0 = __sinf(src_tw[s*32 + lane]*t + src_tb[s*32 + lane]) * h0;
      x2 = edge_h[(size_t)e*32 + lane];
    }
    float x1 = h1;
    float mu = wred(x0 + x1 + x2) * (1.f/160.f);
    float d0 = x0-mu, d1 = x1-mu, d2 = (lane<32) ? (x2-mu) : 0.f;
    float var = wred(d0*d0 + d1*d1 + d2*d2) * (1.f/160.f);
    float sc = rsqrtf(var + 1e-5f);
    size_t bo = (size_t)p*160;
    dia_s[bo + lane]      = f2bf(d0*sc*g_s[lane]      + b_s[lane]);
    dia_s[bo + 64 + lane] = f2bf(d1*sc*g_s[64+lane]   + b_s[64+lane]);
    if(lane < 32)
      dia_s[bo + 128 + lane] = f2bf(d2*sc*g_s[128+lane] + b_s[128+lane]);
  }
  { // dia_d: LN(128)
    float h0 = src_h[(size_t)d*128 + lane];
    float h1 = src_h[(size_t)d*128 + 64 + lane];
    float x0 = (lane < 32) ? __sinf(src_tw[d*32+lane]*t + src_tb[d*32+lane]) * h0 : h0;
    float x1 = h1;
    float mu = wred(x0 + x1) * (1.f/128.f);
    float d0 = x0-mu, d1 = x1-mu;
    float var = wred(d0*d0 + d1*d1) * (1.f/128.f);
    float sc = rsqrtf(var + 1e-5f);
    size_t bo = (size_t)p*128;
    dia_d[bo + lane]      = f2bf(d0*sc*g_d[lane]    + b_d[lane]);
    dia_d[bo + 64 + lane] = f2bf(d1*sc*g_d[64+lane] + b_d[64+lane]);
  }
}

// ---------------- shared GEMM core: 64 rows x 128 cols, wave = 64 rows x 32 cols
// A in LDS [64][lda] bf16; W global bf16 [128 n][Kd k]; Bt LDS chunk [128][40]
__device__ __forceinline__ void gemm64(
  const unsigned short* __restrict__ A, int lda,
  const unsigned short* __restrict__ Wg, int Kd,
  unsigned short* __restrict__ Bt, f32x4* acc, int tid)
{
  int lane = tid & 63, w = tid >> 6, m = lane & 15, quad = lane >> 4;
  #pragma unroll
  for(int i=0;i<8;i++) acc[i] = (f32x4){0.f,0.f,0.f,0.f};
  for(int k0=0; k0<Kd; k0+=32){
    __syncthreads();                       // Bt reuse barrier
    // stage full 128 x 32 bf16 weight chunk: 512 int4 stores, 2 per thread
    #pragma unroll
    for(int j=0;j<2;j++){
      int idx = j*256 + tid;               // 0..511
      int n = idx >> 2, qc = idx & 3;      // row 0..127, quarter 0..3
      *(int4*)(Bt + n*40 + qc*8) = *(const int4*)(Wg + (size_t)n*Kd + k0 + qc*8);
    }
    __syncthreads();
    short8 b0 = *(const short8*)(Bt + (w*32 +      m)*40 + quad*8);
    short8 b1 = *(const short8*)(Bt + (w*32 + 16 + m)*40 + quad*8);
    #pragma unroll
    for(int rt=0; rt<4; rt++){
      short8 af = *(const short8*)(A + (rt*16 + m)*lda + k0 + quad*8);
      acc[rt*2+0] = __builtin_amdgcn_mfma_f32_16x16x32_bf16(af, b0, acc[rt*2+0], 0,0,0);
      acc[rt*2+1] = __builtin_amdgcn_mfma_f32_16x16x32_bf16(af, b1, acc[rt*2+1], 0,0,0);
    }
  }
}

// ---------------- fused typed q/k/v GEMM + attention scores
__global__ __launch_bounds__(256) void k_qkv(
  const unsigned short* __restrict__ dia_d, const unsigned short* __restrict__ dia_s,
  const unsigned short* __restrict__ Wq_t, const unsigned short* __restrict__ Wk_t,
  const unsigned short* __restrict__ Wv_t,
  const int* __restrict__ cnt_e, const int* __restrict__ off_e,
  float* __restrict__ abuf, unsigned short* __restrict__ vbuf)
{
  __shared__ unsigned short Ad[64*136];
  __shared__ unsigned short As[64*168];
  __shared__ unsigned short Bt[128*40];
  int bid = blockIdx.x;
  int r = -1, tl0 = 0, accT = 0;
  #pragma unroll
  for(int i=0;i<8;i++){
    int n = cnt_e[i], tt = (n + 63) >> 6;
    if(r < 0 && bid < accT + tt){ r = i; tl0 = bid - accT; }
    accT += tt;
  }
  if(r < 0) return;
  int row0 = off_e[r] + tl0*64;
  int nv = min(64, cnt_e[r] - tl0*64);
  int tid = threadIdx.x;
  {
    int4 z = make_int4(0,0,0,0);
    #pragma unroll
    for(int it=0; it<4; it++){            // stage dia_d tile
      int idx = it*256 + tid, row = idx >> 4, c = idx & 15;
      int4 v = z;
      if(row < nv) v = *(const int4*)(dia_d + (size_t)(row0+row)*128 + c*8);
      *(int4*)(Ad + row*136 + c*8) = v;
    }
    #pragma unroll
    for(int it=0; it<5; it++){            // stage dia_s tile
      int idx = it*256 + tid, row = idx/20, c = idx%20;
      int4 v = z;
      if(row < nv) v = *(const int4*)(dia_s + (size_t)(row0+row)*160 + c*8);
      *(int4*)(As + row*168 + c*8) = v;
    }
  }
  int lane = tid & 63, w = tid >> 6, m = lane & 15, quad = lane >> 4;
  f32x4 q[8], kk[8], vv[8];
  gemm64(Ad, 136, Wq_t + r*16384, 128, Bt, q,  tid);
  gemm64(As, 168, Wk_t + r*20480, 160, Bt, kk, tid);
  // a[row][head] = sum over 16 cols of head-tile of q*k / sqrt(128)
  const float inv = 0.08838834764831845f;
  #pragma unroll
  for(int rt=0; rt<4; rt++)
  #pragma unroll
  for(int ct=0; ct<2; ct++){
    #pragma unroll
    for(int reg=0; reg<4; reg++){
      float s = q[rt*2+ct][reg] * kk[rt*2+ct][reg];
      s += __shfl_xor(s,1); s += __shfl_xor(s,2); s += __shfl_xor(s,4); s += __shfl_xor(s,8);
      int row = rt*16 + quad*4 + reg;
      if(m == 0 && row < nv) abuf[(size_t)(row0+row)*8 + w*2 + ct] = s * inv;
    }
  }
  gemm64(As, 168, Wv_t + r*20480, 160, Bt, vv, tid);
  #pragma unroll
  for(int rt=0; rt<4; rt++)
  #pragma unroll
  for(int ct=0; ct<2; ct++)
  #pragma unroll
  for(int reg=0; reg<4; reg++){
    int row = rt*16 + quad*4 + reg;
    if(row < nv)
      vbuf[(size_t)(row0+row)*128 + w*32 + ct*16 + m] = f2bf(vv[rt*2+ct][reg]);
  }
}

// ---------------- per-dst softmax + weighted aggregate (no global atomics)
__global__ __launch_bounds__(128) void k_aggr(
  const float* __restrict__ abuf, const unsigned short* __restrict__ vbuf,
  const int* __restrict__ dstlist, const int* __restrict__ off_d,
  const int* __restrict__ npos, const int* __restrict__ ntype,
  const float* __restrict__ h_bias, unsigned short* __restrict__ hpre)
{
  int d = blockIdx.x, tid = threadIdx.x;
  int o0 = off_d[d], cnt = off_d[d+1] - o0;
  __shared__ float den[8];
  if(tid < 8) den[tid] = 0.f;
  __syncthreads();
  for(int idx = tid; idx < cnt*8; idx += 128){
    int i = idx >> 3, h = idx & 7;
    float ex = __expf(abuf[(size_t)dstlist[o0+i]*8 + h]);
    atomicAdd(&den[h], ex);
  }
  __syncthreads();
  int h = tid >> 4;
  float dh = den[h];
  float rd = (dh > 0.f) ? (1.f/dh) : 0.f;
  float acc = 0.f;
  for(int i=0; i<cnt; i++){
    int p = dstlist[o0+i];
    float al = __expf(abuf[(size_t)p*8 + h]) * rd;
    acc += al * bf2f(vbuf[(size_t)p*128 + tid]);
  }
  int t = ntype[d];
  acc += h_bias[t*128 + tid];
  hpre[(size_t)npos[d]*128 + tid] = f2bf(acc);   // write at ntype-sorted row
}

// ---------------- final typed GEMM (Wa) + gate + residual
__global__ __launch_bounds__(256) void k_final(
  const unsigned short* __restrict__ hpre, const unsigned short* __restrict__ Wa_t,
  const int* __restrict__ cnt_n, const int* __restrict__ off_n, const int* __restrict__ nperm,
  const float* __restrict__ skip, const float* __restrict__ src_h, float* __restrict__ out)
{
  __shared__ unsigned short Ah[64*136];
  __shared__ unsigned short Bt[128*40];
  int bid = blockIdx.x;
  int r = -1, tl0 = 0, accT = 0;
  #pragma unroll
  for(int i=0;i<4;i++){
    int n = cnt_n[i], tt = (n + 63) >> 6;
    if(r < 0 && bid < accT + tt){ r = i; tl0 = bid - accT; }
    accT += tt;
  }
  if(r < 0) return;
  int row0 = off_n[r] + tl0*64;
  int nv = min(64, cnt_n[r] - tl0*64);
  float gate = 1.f / (1.f + __expf(-skip[r]));
  int tid = threadIdx.x;
  int4 z = make_int4(0,0,0,0);
  #pragma unroll
  for(int it=0; it<4; it++){
    int idx = it*256 + tid, row = idx >> 4, c = idx & 15;
    int4 v = z;
    if(row < nv) v = *(const int4*)(hpre + (size_t)(row0+row)*128 + c*8);
    *(int4*)(Ah + row*136 + c*8) = v;
  }
  f32x4 acc[8];
  gemm64(Ah, 136, Wa_t + r*16384, 128, Bt, acc, tid);
  int lane = tid & 63, w = tid >> 6, m = lane & 15, quad = lane >> 4;
  #pragma unroll
  for(int rt=0; rt<4; rt++)
  #pragma unroll
  for(int ct=0; ct<2; ct++)
  #pragma unroll
  for(int reg=0; reg<4; reg++){
    int row = rt*16 + quad*4 + reg;
    if(row < nv){
      int dd = nperm[row0+row];
      int col = w*32 + ct*16 + m;
      out[(size_t)dd*128 + col] = acc[rt*2+ct][reg]*gate + src_h[(size_t)dd*128 + col]*(1.f - gate);
    }
  }
}

// ---------------------------------------------------------------------------
extern "C" void kernel_launch(void* const* d_in, const int* in_sizes, int n_in,
                              void* d_out, int out_size, void* d_ws, size_t ws_size,
                              hipStream_t stream)
{
  const float* src_h  = (const float*)d_in[0];
  const float* src_tw = (const float*)d_in[1];
  const float* src_tb = (const float*)d_in[2];
  const float* edge_h = (const float*)d_in[3];
  const float* date   = (const float*)d_in[4];
  const int*   src_idx= (const int*)d_in[5];
  const int*   dst_idx= (const int*)d_in[6];
  const int*   etype  = (const int*)d_in[7];
  const int*   ntype  = (const int*)d_in[8];
  const float* Wq     = (const float*)d_in[9];
  const float* Wk     = (const float*)d_in[10];
  const float* Wv     = (const float*)d_in[11];
  const float* Wa     = (const float*)d_in[12];
  const float* h_bias = (const float*)d_in[13];
  const float* skip   = (const float*)d_in[14];
  const float* g_s    = (const float*)d_in[15];
  const float* b_s    = (const float*)d_in[16];
  const float* g_d    = (const float*)d_in[17];
  const float* b_d    = (const float*)d_in[18];
  float* out = (float*)d_out;

  const int E = in_sizes[4];   // date
  const int M = in_sizes[8];   // ntype

  char* base = (char*)d_ws;
  size_t off = 0;
  auto alloc = [&](size_t bytes)->char*{
    off = (off + 255) & ~(size_t)255;
    char* p = base + off; off += bytes; return p;
  };
  // contiguous zero region: cnt_e[8] cur_e[8] cnt_n[4] cur_n[4] cnt_d[M] cur_d[M]
  int* cnt_e = (int*)alloc((size_t)(24 + 2*M)*4);
  int* cur_e = cnt_e + 8;
  int* cnt_n = cur_e + 8;
  int* cur_n = cnt_n + 4;
  int* cnt_d = cur_n + 4;
  int* cur_d = cnt_d + M;
  const int nzero = 24 + 2*M;
  int* off_e = (int*)alloc(9*4);
  int* off_n = (int*)alloc(5*4);
  int* off_d = (int*)alloc((size_t)(M+1)*4);
  int* eperm   = (int*)alloc((size_t)E*4);
  int* dstlist = (int*)alloc((size_t)E*4);
  int* nperm   = (int*)alloc((size_t)M*4);
  int* npos    = (int*)alloc((size_t)M*4);
  unsigned short* Wq_t = (unsigned short*)alloc((size_t)8*128*128*2);
  unsigned short* Wk_t = (unsigned short*)alloc((size_t)8*160*128*2);
  unsigned short* Wv_t = (unsigned short*)alloc((size_t)8*160*128*2);
  unsigned short* Wa_t = (unsigned short*)alloc((size_t)4*128*128*2);
  unsigned short* dia_d = (unsigned short*)alloc((size_t)E*128*2);
  unsigned short* dia_s = (unsigned short*)alloc((size_t)E*160*2);
  unsigned short* vbuf  = (unsigned short*)alloc((size_t)E*128*2);
  unsigned short* hpre  = (unsigned short*)alloc((size_t)M*128*2);
  float* abuf = (float*)alloc((size_t)E*8*4);

  k_zero<<<dim3((nzero+255)/256), dim3(256), 0, stream>>>(cnt_e, nzero);
  k_hist<<<dim3((E+255)/256), dim3(256), 0, stream>>>(etype, dst_idx, ntype, cnt_e, cnt_d, cnt_n, E, M);
  k_scan<<<dim3(1), dim3(1024), 0, stream>>>(cnt_e, off_e, cnt_n, off_n, cnt_d, off_d, M);
  k_scatter<<<dim3((E+255)/256), dim3(256), 0, stream>>>(etype, dst_idx, ntype,
      off_e, cur_e, off_d, cur_d, off_n, cur_n, eperm, dstlist, nperm, npos, E, M);
  k_convw<<<dim3(2048), dim3(256), 0, stream>>>(Wq, Wk, Wv, Wa, Wq_t, Wk_t, Wv_t, Wa_t);
  k_prep<<<dim3((E+3)/4), dim3(256), 0, stream>>>(src_h, src_tw, src_tb, edge_h, date,
      src_idx, dst_idx, eperm, g_s, b_s, g_d, b_d, dia_s, dia_d, E);
  k_qkv<<<dim3(E/64 + 9), dim3(256), 0, stream>>>(dia_d, dia_s, Wq_t, Wk_t, Wv_t,
      cnt_e, off_e, abuf, vbuf);
  k_aggr<<<dim3(M), dim3(128), 0, stream>>>(abuf, vbuf, dstlist, off_d, npos, ntype, h_bias, hpre);
  k_final<<<dim3(M/64 + 5), dim3(256), 0, stream>>>(hpre, Wa_t, cnt_n, off_n, nperm, skip, src_h, out);
}

// Round 3
// 290.001 us; speedup vs baseline: 3.7278x; 3.7278x over previous
//
#include <hip/hip_runtime.h>

// ---------------------------------------------------------------------------
// HTGT layer: sort-by-type + bf16 MFMA pipeline
// dims (fixed by problem): N=50000 M=10000 E=100000, in=128 e=32 out=128 td=32
// R=8 etypes, T=4 ntypes, H=8 heads, hs=16
// R2: k_hist/k_scatter hot-counter atomics hierarchized (was 414us of
//     8-address global atomic serialization -> ~3k global atomics total)
// ---------------------------------------------------------------------------

typedef __attribute__((ext_vector_type(8))) short short8;
typedef __attribute__((ext_vector_type(4))) float f32x4;

__device__ __forceinline__ unsigned short f2bf(float f){
  union { float f; unsigned u; } x; x.f = f;
  unsigned r = x.u + 0x7FFFu + ((x.u >> 16) & 1u);
  return (unsigned short)(r >> 16);
}
__device__ __forceinline__ float bf2f(unsigned short b){
  union { unsigned u; float f; } x; x.u = ((unsigned)b) << 16;
  return x.f;
}
__device__ __forceinline__ float wred(float v){
  #pragma unroll
  for(int i=1;i<64;i<<=1) v += __shfl_xor(v, i);
  return v;
}

// ---------------- setup kernels ----------------

__global__ void k_zero(int* __restrict__ p, int n){
  int i = blockIdx.x*256 + threadIdx.x;
  if(i < n) p[i] = 0;
}

__global__ __launch_bounds__(256) void k_hist(
    const int* __restrict__ etype, const int* __restrict__ dst_idx,
    const int* __restrict__ ntype,
    int* cnt_e, int* cnt_d, int* cnt_n, int E, int M){
  __shared__ int le[8], ln[4];
  int tid = threadIdx.x;
  if(tid < 8) le[tid] = 0;
  if(tid < 4) ln[tid] = 0;
  __syncthreads();
  int g = blockIdx.x*256 + tid;
  if(g < E){ atomicAdd(&le[etype[g]], 1); atomicAdd(&cnt_d[dst_idx[g]], 1); }
  if(g < M){ atomicAdd(&ln[ntype[g]], 1); }
  __syncthreads();
  if(tid < 8 && le[tid]) atomicAdd(&cnt_e[tid], le[tid]);
  if(tid < 4 && ln[tid]) atomicAdd(&cnt_n[tid], ln[tid]);
}

__global__ __launch_bounds__(1024) void k_scan(const int* __restrict__ cnt_e, int* off_e,
                                               const int* __restrict__ cnt_n, int* off_n,
                                               const int* __restrict__ cnt_d, int* off_d, int M){
  __shared__ int part[1024];
  int tid = threadIdx.x;
  if(tid == 0){
    int s = 0;
    for(int i=0;i<8;i++){ off_e[i]=s; s+=cnt_e[i]; } off_e[8]=s;
    s = 0;
    for(int i=0;i<4;i++){ off_n[i]=s; s+=cnt_n[i]; } off_n[4]=s;
  }
  int per = (M + 1023) >> 10;
  int s = 0;
  for(int j=0;j<per;j++){ int idx = tid*per + j; if(idx < M) s += cnt_d[idx]; }
  part[tid] = s; __syncthreads();
  for(int o=1;o<1024;o<<=1){
    int v = (tid >= o) ? part[tid-o] : 0;
    __syncthreads();
    part[tid] += v;
    __syncthreads();
  }
  int run = (tid == 0) ? 0 : part[tid-1];
  for(int j=0;j<per;j++){
    int idx = tid*per + j;
    if(idx < M){ off_d[idx] = run; run += cnt_d[idx]; }
  }
  if(tid == 1023) off_d[M] = run;
}

__global__ __launch_bounds__(256) void k_scatter(
    const int* __restrict__ etype, const int* __restrict__ dst_idx,
    const int* __restrict__ ntype,
    const int* __restrict__ off_e, int* cur_e,
    const int* __restrict__ off_d, int* cur_d,
    const int* __restrict__ off_n, int* cur_n,
    int* eperm, int* dstlist, int* nperm, int* npos, int E, int M){
  __shared__ int lcnt[8], lbase[8], lnc[4], lnb[4];
  int tid = threadIdx.x;
  if(tid < 8) lcnt[tid] = 0;
  if(tid < 4) lnc[tid] = 0;
  __syncthreads();
  int g = blockIdx.x*256 + tid;
  int r = 0, lrank = 0, t = 0, nrank = 0;
  bool inE = (g < E), inM = (g < M);
  if(inE){ r = etype[g]; lrank = atomicAdd(&lcnt[r], 1); }
  if(inM){ t = ntype[g]; nrank = atomicAdd(&lnc[t], 1); }
  __syncthreads();
  if(tid < 8 && lcnt[tid]) lbase[tid] = atomicAdd(&cur_e[tid], lcnt[tid]);
  if(tid < 4 && lnc[tid])  lnb[tid]   = atomicAdd(&cur_n[tid], lnc[tid]);
  __syncthreads();
  if(inE){
    int p = off_e[r] + lbase[r] + lrank;
    eperm[p] = g;
    int d = dst_idx[g];
    int q = off_d[d] + atomicAdd(&cur_d[d], 1);   // ~10-way contention, benign
    dstlist[q] = p;                               // etype-sorted position
  }
  if(inM){
    int np = off_n[t] + lnb[t] + nrank;
    npos[g] = np;
    nperm[np] = g;
  }
}

// convert + transpose weights to bf16 [r][n][k] layout (B-operand friendly)
__global__ void k_convw(const float* __restrict__ Wq, const float* __restrict__ Wk,
                        const float* __restrict__ Wv, const float* __restrict__ Wa,
                        unsigned short* Wq_t, unsigned short* Wk_t,
                        unsigned short* Wv_t, unsigned short* Wa_t){
  int tid = blockIdx.x*256 + threadIdx.x;
  if(tid < 131072){                                  // Wq: 8 x 128 x 128
    int r = tid >> 14, rem = tid & 16383, i = rem >> 7, o = rem & 127;
    Wq_t[(r<<14) + (o<<7) + i] = f2bf(Wq[tid]);
  } else if(tid < 294912){                           // Wk: 8 x 160 x 128
    int u = tid - 131072;
    int r = u / 20480, rem = u - r*20480, i = rem >> 7, o = rem & 127;
    Wk_t[r*20480 + o*160 + i] = f2bf(Wk[u]);
  } else if(tid < 458752){                           // Wv: 8 x 160 x 128
    int u = tid - 294912;
    int r = u / 20480, rem = u - r*20480, i = rem >> 7, o = rem & 127;
    Wv_t[r*20480 + o*160 + i] = f2bf(Wv[u]);
  } else if(tid < 524288){                           // Wa: 4 x 128 x 128
    int u = tid - 458752;
    int r = u >> 14, rem = u & 16383, i = rem >> 7, o = rem & 127;
    Wa_t[(r<<14) + (o<<7) + i] = f2bf(Wa[u]);
  }
}

// ---------------- prep: gather + temporal encode + LN, written in etype-sorted order
__global__ __launch_bounds__(256) void k_prep(
  const float* __restrict__ src_h, const float* __restrict__ src_tw, const float* __restrict__ src_tb,
  const float* __restrict__ edge_h, const float* __restrict__ date,
  const int* __restrict__ src_idx, const int* __restrict__ dst_idx, const int* __restrict__ eperm,
  const float* __restrict__ g_s, const float* __restrict__ b_s,
  const float* __restrict__ g_d, const float* __restrict__ b_d,
  unsigned short* __restrict__ dia_s, unsigned short* __restrict__ dia_d, int E)
{
  int p = blockIdx.x*4 + (threadIdx.x >> 6);
  if(p >= E) return;
  int lane = threadIdx.x & 63;
  int e = eperm[p];
  float t = date[e];
  int s = src_idx[e], d = dst_idx[e];
  { // dia_s: [sin(tw*t+tb)*h[:32], h[32:128], edge_h] -> LN(160)
    float h0 = src_h[(size_t)s*128 + lane];
    float h1 = src_h[(size_t)s*128 + 64 + lane];
    float x0 = h0, x2 = 0.f;
    if(lane < 32){
      x0 = __sinf(src_tw[s*32 + lane]*t + src_tb[s*32 + lane]) * h0;
      x2 = edge_h[(size_t)e*32 + lane];
    }
    float x1 = h1;
    float mu = wred(x0 + x1 + x2) * (1.f/160.f);
    float d0 = x0-mu, d1 = x1-mu, d2 = (lane<32) ? (x2-mu) : 0.f;
    float var = wred(d0*d0 + d1*d1 + d2*d2) * (1.f/160.f);
    float sc = rsqrtf(var + 1e-5f);
    size_t bo = (size_t)p*160;
    dia_s[bo + lane]      = f2bf(d0*sc*g_s[lane]      + b_s[lane]);
    dia_s[bo + 64 + lane] = f2bf(d1*sc*g_s[64+lane]   + b_s[64+lane]);
    if(lane < 32)
      dia_s[bo + 128 + lane] = f2bf(d2*sc*g_s[128+lane] + b_s[128+lane]);
  }
  { // dia_d: LN(128)
    float h0 = src_h[(size_t)d*128 + lane];
    float h1 = src_h[(size_t)d*128 + 64 + lane];
    float x0 = (lane < 32) ? __sinf(src_tw[d*32+lane]*t + src_tb[d*32+lane]) * h0 : h0;
    float x1 = h1;
    float mu = wred(x0 + x1) * (1.f/128.f);
    float d0 = x0-mu, d1 = x1-mu;
    float var = wred(d0*d0 + d1*d1) * (1.f/128.f);
    float sc = rsqrtf(var + 1e-5f);
    size_t bo = (size_t)p*128;
    dia_d[bo + lane]      = f2bf(d0*sc*g_d[lane]    + b_d[lane]);
    dia_d[bo + 64 + lane] = f2bf(d1*sc*g_d[64+lane] + b_d[64+lane]);
  }
}

// ---------------- shared GEMM core: 64 rows x 128 cols, wave = 64 rows x 32 cols
// A in LDS [64][lda] bf16; W global bf16 [128 n][Kd k]; Bt LDS chunk [128][40]
__device__ __forceinline__ void gemm64(
  const unsigned short* __restrict__ A, int lda,
  const unsigned short* __restrict__ Wg, int Kd,
  unsigned short* __restrict__ Bt, f32x4* acc, int tid)
{
  int lane = tid & 63, w = tid >> 6, m = lane & 15, quad = lane >> 4;
  #pragma unroll
  for(int i=0;i<8;i++) acc[i] = (f32x4){0.f,0.f,0.f,0.f};
  for(int k0=0; k0<Kd; k0+=32){
    __syncthreads();                       // Bt reuse barrier
    // stage full 128 x 32 bf16 weight chunk: 512 int4 stores, 2 per thread
    #pragma unroll
    for(int j=0;j<2;j++){
      int idx = j*256 + tid;               // 0..511
      int n = idx >> 2, qc = idx & 3;      // row 0..127, quarter 0..3
      *(int4*)(Bt + n*40 + qc*8) = *(const int4*)(Wg + (size_t)n*Kd + k0 + qc*8);
    }
    __syncthreads();
    short8 b0 = *(const short8*)(Bt + (w*32 +      m)*40 + quad*8);
    short8 b1 = *(const short8*)(Bt + (w*32 + 16 + m)*40 + quad*8);
    #pragma unroll
    for(int rt=0; rt<4; rt++){
      short8 af = *(const short8*)(A + (rt*16 + m)*lda + k0 + quad*8);
      acc[rt*2+0] = __builtin_amdgcn_mfma_f32_16x16x32_bf16(af, b0, acc[rt*2+0], 0,0,0);
      acc[rt*2+1] = __builtin_amdgcn_mfma_f32_16x16x32_bf16(af, b1, acc[rt*2+1], 0,0,0);
    }
  }
}

// ---------------- fused typed q/k/v GEMM + attention scores
__global__ __launch_bounds__(256) void k_qkv(
  const unsigned short* __restrict__ dia_d, const unsigned short* __restrict__ dia_s,
  const unsigned short* __restrict__ Wq_t, const unsigned short* __restrict__ Wk_t,
  const unsigned short* __restrict__ Wv_t,
  const int* __restrict__ cnt_e, const int* __restrict__ off_e,
  float* __restrict__ abuf, unsigned short* __restrict__ vbuf)
{
  __shared__ unsigned short Ad[64*136];
  __shared__ unsigned short As[64*168];
  __shared__ unsigned short Bt[128*40];
  int bid = blockIdx.x;
  int r = -1, tl0 = 0, accT = 0;
  #pragma unroll
  for(int i=0;i<8;i++){
    int n = cnt_e[i], tt = (n + 63) >> 6;
    if(r < 0 && bid < accT + tt){ r = i; tl0 = bid - accT; }
    accT += tt;
  }
  if(r < 0) return;
  int row0 = off_e[r] + tl0*64;
  int nv = min(64, cnt_e[r] - tl0*64);
  int tid = threadIdx.x;
  {
    int4 z = make_int4(0,0,0,0);
    #pragma unroll
    for(int it=0; it<4; it++){            // stage dia_d tile
      int idx = it*256 + tid, row = idx >> 4, c = idx & 15;
      int4 v = z;
      if(row < nv) v = *(const int4*)(dia_d + (size_t)(row0+row)*128 + c*8);
      *(int4*)(Ad + row*136 + c*8) = v;
    }
    #pragma unroll
    for(int it=0; it<5; it++){            // stage dia_s tile
      int idx = it*256 + tid, row = idx/20, c = idx%20;
      int4 v = z;
      if(row < nv) v = *(const int4*)(dia_s + (size_t)(row0+row)*160 + c*8);
      *(int4*)(As + row*168 + c*8) = v;
    }
  }
  int lane = tid & 63, w = tid >> 6, m = lane & 15, quad = lane >> 4;
  f32x4 q[8], kk[8], vv[8];
  gemm64(Ad, 136, Wq_t + r*16384, 128, Bt, q,  tid);
  gemm64(As, 168, Wk_t + r*20480, 160, Bt, kk, tid);
  // a[row][head] = sum over 16 cols of head-tile of q*k / sqrt(128)
  const float inv = 0.08838834764831845f;
  #pragma unroll
  for(int rt=0; rt<4; rt++)
  #pragma unroll
  for(int ct=0; ct<2; ct++){
    #pragma unroll
    for(int reg=0; reg<4; reg++){
      float s = q[rt*2+ct][reg] * kk[rt*2+ct][reg];
      s += __shfl_xor(s,1); s += __shfl_xor(s,2); s += __shfl_xor(s,4); s += __shfl_xor(s,8);
      int row = rt*16 + quad*4 + reg;
      if(m == 0 && row < nv) abuf[(size_t)(row0+row)*8 + w*2 + ct] = s * inv;
    }
  }
  gemm64(As, 168, Wv_t + r*20480, 160, Bt, vv, tid);
  #pragma unroll
  for(int rt=0; rt<4; rt++)
  #pragma unroll
  for(int ct=0; ct<2; ct++)
  #pragma unroll
  for(int reg=0; reg<4; reg++){
    int row = rt*16 + quad*4 + reg;
    if(row < nv)
      vbuf[(size_t)(row0+row)*128 + w*32 + ct*16 + m] = f2bf(vv[rt*2+ct][reg]);
  }
}

// ---------------- per-dst softmax + weighted aggregate (no global atomics)
__global__ __launch_bounds__(128) void k_aggr(
  const float* __restrict__ abuf, const unsigned short* __restrict__ vbuf,
  const int* __restrict__ dstlist, const int* __restrict__ off_d,
  const int* __restrict__ npos, const int* __restrict__ ntype,
  const float* __restrict__ h_bias, unsigned short* __restrict__ hpre)
{
  int d = blockIdx.x, tid = threadIdx.x;
  int o0 = off_d[d], cnt = off_d[d+1] - o0;
  __shared__ float den[8];
  if(tid < 8) den[tid] = 0.f;
  __syncthreads();
  for(int idx = tid; idx < cnt*8; idx += 128){
    int i = idx >> 3, h = idx & 7;
    float ex = __expf(abuf[(size_t)dstlist[o0+i]*8 + h]);
    atomicAdd(&den[h], ex);
  }
  __syncthreads();
  int h = tid >> 4;
  float dh = den[h];
  float rd = (dh > 0.f) ? (1.f/dh) : 0.f;
  float acc = 0.f;
  for(int i=0; i<cnt; i++){
    int p = dstlist[o0+i];
    float al = __expf(abuf[(size_t)p*8 + h]) * rd;
    acc += al * bf2f(vbuf[(size_t)p*128 + tid]);
  }
  int t = ntype[d];
  acc += h_bias[t*128 + tid];
  hpre[(size_t)npos[d]*128 + tid] = f2bf(acc);   // write at ntype-sorted row
}

// ---------------- final typed GEMM (Wa) + gate + residual
__global__ __launch_bounds__(256) void k_final(
  const unsigned short* __restrict__ hpre, const unsigned short* __restrict__ Wa_t,
  const int* __restrict__ cnt_n, const int* __restrict__ off_n, const int* __restrict__ nperm,
  const float* __restrict__ skip, const float* __restrict__ src_h, float* __restrict__ out)
{
  __shared__ unsigned short Ah[64*136];
  __shared__ unsigned short Bt[128*40];
  int bid = blockIdx.x;
  int r = -1, tl0 = 0, accT = 0;
  #pragma unroll
  for(int i=0;i<4;i++){
    int n = cnt_n[i], tt = (n + 63) >> 6;
    if(r < 0 && bid < accT + tt){ r = i; tl0 = bid - accT; }
    accT += tt;
  }
  if(r < 0) return;
  int row0 = off_n[r] + tl0*64;
  int nv = min(64, cnt_n[r] - tl0*64);
  float gate = 1.f / (1.f + __expf(-skip[r]));
  int tid = threadIdx.x;
  int4 z = make_int4(0,0,0,0);
  #pragma unroll
  for(int it=0; it<4; it++){
    int idx = it*256 + tid, row = idx >> 4, c = idx & 15;
    int4 v = z;
    if(row < nv) v = *(const int4*)(hpre + (size_t)(row0+row)*128 + c*8);
    *(int4*)(Ah + row*136 + c*8) = v;
  }
  f32x4 acc[8];
  gemm64(Ah, 136, Wa_t + r*16384, 128, Bt, acc, tid);
  int lane = tid & 63, w = tid >> 6, m = lane & 15, quad = lane >> 4;
  #pragma unroll
  for(int rt=0; rt<4; rt++)
  #pragma unroll
  for(int ct=0; ct<2; ct++)
  #pragma unroll
  for(int reg=0; reg<4; reg++){
    int row = rt*16 + quad*4 + reg;
    if(row < nv){
      int dd = nperm[row0+row];
      int col = w*32 + ct*16 + m;
      out[(size_t)dd*128 + col] = acc[rt*2+ct][reg]*gate + src_h[(size_t)dd*128 + col]*(1.f - gate);
    }
  }
}

// ---------------------------------------------------------------------------
extern "C" void kernel_launch(void* const* d_in, const int* in_sizes, int n_in,
                              void* d_out, int out_size, void* d_ws, size_t ws_size,
                              hipStream_t stream)
{
  const float* src_h  = (const float*)d_in[0];
  const float* src_tw = (const float*)d_in[1];
  const float* src_tb = (const float*)d_in[2];
  const float* edge_h = (const float*)d_in[3];
  const float* date   = (const float*)d_in[4];
  const int*   src_idx= (const int*)d_in[5];
  const int*   dst_idx= (const int*)d_in[6];
  const int*   etype  = (const int*)d_in[7];
  const int*   ntype  = (const int*)d_in[8];
  const float* Wq     = (const float*)d_in[9];
  const float* Wk     = (const float*)d_in[10];
  const float* Wv     = (const float*)d_in[11];
  const float* Wa     = (const float*)d_in[12];
  const float* h_bias = (const float*)d_in[13];
  const float* skip   = (const float*)d_in[14];
  const float* g_s    = (const float*)d_in[15];
  const float* b_s    = (const float*)d_in[16];
  const float* g_d    = (const float*)d_in[17];
  const float* b_d    = (const float*)d_in[18];
  float* out = (float*)d_out;

  const int E = in_sizes[4];   // date
  const int M = in_sizes[8];   // ntype

  char* base = (char*)d_ws;
  size_t off = 0;
  auto alloc = [&](size_t bytes)->char*{
    off = (off + 255) & ~(size_t)255;
    char* p = base + off; off += bytes; return p;
  };
  // contiguous zero region: cnt_e[8] cur_e[8] cnt_n[4] cur_n[4] cnt_d[M] cur_d[M]
  int* cnt_e = (int*)alloc((size_t)(24 + 2*M)*4);
  int* cur_e = cnt_e + 8;
  int* cnt_n = cur_e + 8;
  int* cur_n = cnt_n + 4;
  int* cnt_d = cur_n + 4;
  int* cur_d = cnt_d + M;
  const int nzero = 24 + 2*M;
  int* off_e = (int*)alloc(9*4);
  int* off_n = (int*)alloc(5*4);
  int* off_d = (int*)alloc((size_t)(M+1)*4);
  int* eperm   = (int*)alloc((size_t)E*4);
  int* dstlist = (int*)alloc((size_t)E*4);
  int* nperm   = (int*)alloc((size_t)M*4);
  int* npos    = (int*)alloc((size_t)M*4);
  unsigned short* Wq_t = (unsigned short*)alloc((size_t)8*128*128*2);
  unsigned short* Wk_t = (unsigned short*)alloc((size_t)8*160*128*2);
  unsigned short* Wv_t = (unsigned short*)alloc((size_t)8*160*128*2);
  unsigned short* Wa_t = (unsigned short*)alloc((size_t)4*128*128*2);
  unsigned short* dia_d = (unsigned short*)alloc((size_t)E*128*2);
  unsigned short* dia_s = (unsigned short*)alloc((size_t)E*160*2);
  unsigned short* vbuf  = (unsigned short*)alloc((size_t)E*128*2);
  unsigned short* hpre  = (unsigned short*)alloc((size_t)M*128*2);
  float* abuf = (float*)alloc((size_t)E*8*4);

  k_zero<<<dim3((nzero+255)/256), dim3(256), 0, stream>>>(cnt_e, nzero);
  k_hist<<<dim3((E+255)/256), dim3(256), 0, stream>>>(etype, dst_idx, ntype, cnt_e, cnt_d, cnt_n, E, M);
  k_scan<<<dim3(1), dim3(1024), 0, stream>>>(cnt_e, off_e, cnt_n, off_n, cnt_d, off_d, M);
  k_scatter<<<dim3((E+255)/256), dim3(256), 0, stream>>>(etype, dst_idx, ntype,
      off_e, cur_e, off_d, cur_d, off_n, cur_n, eperm, dstlist, nperm, npos, E, M);
  k_convw<<<dim3(2048), dim3(256), 0, stream>>>(Wq, Wk, Wv, Wa, Wq_t, Wk_t, Wv_t, Wa_t);
  k_prep<<<dim3((E+3)/4), dim3(256), 0, stream>>>(src_h, src_tw, src_tb, edge_h, date,
      src_idx, dst_idx, eperm, g_s, b_s, g_d, b_d, dia_s, dia_d, E);
  k_qkv<<<dim3(E/64 + 9), dim3(256), 0, stream>>>(dia_d, dia_s, Wq_t, Wk_t, Wv_t,
      cnt_e, off_e, abuf, vbuf);
  k_aggr<<<dim3(M), dim3(128), 0, stream>>>(abuf, vbuf, dstlist, off_d, npos, ntype, h_bias, hpre);
  k_final<<<dim3(M/64 + 5), dim3(256), 0, stream>>>(hpre, Wa_t, cnt_n, off_n, nperm, skip, src_h, out);
}